// Round 1
// baseline (224.854 us; speedup 1.0000x reference)
//
#include <hip/hip_runtime.h>
#include <math.h>

#define MARGIN 0.3f
#define BIGF 1e9f
#define NN 512
#define DD 2048
#define LDIM 128
#define PARTS 8

typedef __attribute__((ext_vector_type(8))) __bf16 bf16x8;
typedef __attribute__((ext_vector_type(4))) float f32x4;

// LDS overlay: gram phase needs 32 KB (double-buffered A/B tiles); mine phase
// needs ~12.7 KB. Union keeps the block at 32 KB -> 2 blocks/CU resident
// (64 KB of 160 KB), which guarantees all 512 blocks co-resident for the
// device-scope spin barrier (grid == 2 blocks/CU * 256 CUs exactly).
union SMem {
  struct { __bf16 A[2][4096]; __bf16 B[2][4096]; } g;            // 32 KB
  struct {
    float A2[LDIM * PARTS];                                      // 4 KB
    float B2[2][LDIM * PARTS];                                   // 8 KB
    float dtm[2][64];
    float res[2];
    float apv[4]; float anv[4];
    int   api[4]; int   ani[4];
    int   pn[2];
  } m;
};

// ---------------------------------------------------------------------------
// Fused kernel. Phase A: block b computes gram tile (ti,tj,ks) of G = X X^T
// via bf16 MFMA (split-K=8, fp16 partials). Diagonal norms are atomicAdd-
// combined into nsum[512] (zeroed by host-side memsetAsync). Device-scope
// barrier (release fetch_add / acquire spin + threadfences per G16), then
// Phase B: block i mines row i (hard pos/neg) and runs the local DTW loss.
// ---------------------------------------------------------------------------
__global__ __launch_bounds__(256, 2) void k_fused(
    const float* __restrict__ X, const int* __restrict__ tg,
    const float* __restrict__ LF, _Float16* __restrict__ Gp,
    float* __restrict__ nsum, float* gsum, float* lsum,
    unsigned* done, unsigned* fin, float* __restrict__ out)
{
    __shared__ SMem sm;

    const int bid = blockIdx.x;
    const int t = threadIdx.x;
    const int w = t >> 6, lane = t & 63;

    // prefetch LF[bid] for phase B; latency hides under the whole gram phase
    float4 a2v = ((const float4*)(LF + (size_t)bid * LDIM * PARTS))[t];

    // ======================= phase A: gram tile =======================
    {
        const int tj = bid & 7, ti = (bid >> 3) & 7, ks = bid >> 6;
        const int wr = w >> 1, wc = w & 1;
        const int hf = t >> 7;              // 0: stage A rows, 1: stage B rows
        const int r = (t >> 1) & 63;
        const int kst = t & 1;
        const int grow = (hf ? tj : ti) * 64 + r;
        const float4* gp4 = (const float4*)(X + (size_t)grow * DD + ks * 256 + kst * 32);
        const int ebase = kst * 2048 + (r >> 4) * 512 + (r & 15) * 8;

        float4 cur[8];
#pragma unroll
        for (int q = 0; q < 8; q++) cur[q] = gp4[q];

        f32x4 acc00 = {0.f, 0.f, 0.f, 0.f};
        f32x4 acc01 = {0.f, 0.f, 0.f, 0.f};
        f32x4 acc10 = {0.f, 0.f, 0.f, 0.f};
        f32x4 acc11 = {0.f, 0.f, 0.f, 0.f};

        {
            __bf16* hb = (hf ? sm.g.B[0] : sm.g.A[0]) + ebase;
#pragma unroll
            for (int jg = 0; jg < 4; jg++) {
                float fe[8] = {cur[2 * jg].x, cur[2 * jg].y, cur[2 * jg].z, cur[2 * jg].w,
                               cur[2 * jg + 1].x, cur[2 * jg + 1].y, cur[2 * jg + 1].z, cur[2 * jg + 1].w};
                bf16x8 h;
#pragma unroll
                for (int e = 0; e < 8; e++) h[e] = (__bf16)fe[e];
                *(bf16x8*)(hb + jg * 128) = h;
            }
        }

#pragma unroll
        for (int it = 0; it < 4; ++it) {
            __syncthreads();                   // buf[it&1] staged & prior reads done
            if (it < 3) {
                const float4* np = gp4 + (it + 1) * 16;
#pragma unroll
                for (int q = 0; q < 8; q++) cur[q] = np[q];
            }
            int buf = it & 1;
#pragma unroll
            for (int kstep = 0; kstep < 2; kstep++) {
                const bf16x8* fA = (const bf16x8*)&sm.g.A[buf][kstep * 2048 + wr * 1024];
                const bf16x8* fB = (const bf16x8*)&sm.g.B[buf][kstep * 2048 + wc * 1024];
                bf16x8 ah0 = fA[lane], ah1 = fA[lane + 64];
                bf16x8 bh0 = fB[lane], bh1 = fB[lane + 64];
                acc00 = __builtin_amdgcn_mfma_f32_16x16x32_bf16(ah0, bh0, acc00, 0, 0, 0);
                acc01 = __builtin_amdgcn_mfma_f32_16x16x32_bf16(ah0, bh1, acc01, 0, 0, 0);
                acc10 = __builtin_amdgcn_mfma_f32_16x16x32_bf16(ah1, bh0, acc10, 0, 0, 0);
                acc11 = __builtin_amdgcn_mfma_f32_16x16x32_bf16(ah1, bh1, acc11, 0, 0, 0);
            }
            if (it < 3) {
                int nb = (it + 1) & 1;
                __bf16* hb = (hf ? sm.g.B[nb] : sm.g.A[nb]) + ebase;
#pragma unroll
                for (int jg = 0; jg < 4; jg++) {
                    float fe[8] = {cur[2 * jg].x, cur[2 * jg].y, cur[2 * jg].z, cur[2 * jg].w,
                                   cur[2 * jg + 1].x, cur[2 * jg + 1].y, cur[2 * jg + 1].z, cur[2 * jg + 1].w};
                    bf16x8 h;
#pragma unroll
                    for (int e = 0; e < 8; e++) h[e] = (__bf16)fe[e];
                    *(bf16x8*)(hb + jg * 128) = h;
                }
            }
        }

        // epilogue: C/D layout col = lane&15, row = (lane>>4)*4 + reg
        const int rbase = ti * 64 + wr * 32 + ((lane >> 4) << 2);
        const int cbase = tj * 64 + wc * 32 + (lane & 15);
        _Float16* gb = Gp + (size_t)ks * NN * NN;
        f32x4 accs[2][2] = {{acc00, acc01}, {acc10, acc11}};
#pragma unroll
        for (int g2 = 0; g2 < 2; g2++)
#pragma unroll
            for (int h2 = 0; h2 < 2; h2++)
#pragma unroll
                for (int rr = 0; rr < 4; rr++)
                    gb[(size_t)(rbase + g2 * 16 + rr) * NN + cbase + h2 * 16] =
                        (_Float16)accs[g2][h2][rr];

        // diagonal harvest: combine per-ks norms directly into nsum[row]
        if (ti == tj && wr == wc && ((lane >> 4) == ((lane & 15) >> 2))) {
            int rr = lane & 3;
            int row0 = rbase + rr;
            atomicAdd(&nsum[row0],      acc00[rr]);
            atomicAdd(&nsum[row0 + 16], acc11[rr]);
        }
    }

    // ======================= device-scope grid barrier =======================
    __threadfence();                        // agent release: publish Gp stores
    __syncthreads();
    if (t == 0) {
        __hip_atomic_fetch_add(done, 1u, __ATOMIC_ACQ_REL, __HIP_MEMORY_SCOPE_AGENT);
        while (__hip_atomic_load(done, __ATOMIC_ACQUIRE, __HIP_MEMORY_SCOPE_AGENT) < (unsigned)NN)
            __builtin_amdgcn_s_sleep(2);
    }
    __syncthreads();
    __threadfence();                        // agent acquire: invalidate caches

    // ======================= phase B: mining + local DTW =======================
    const int i = bid;
    float ni = nsum[i];                     // uniform -> scalar broadcast
    float2 nj2 = ((const float2*)nsum)[t];
    int2 tg2 = ((const int2*)tg)[t];
    int tgt_i = tg[i];

    float g0 = 0.f, g1 = 0.f;
    {
        const unsigned int* gr = (const unsigned int*)(Gp + (size_t)i * NN);
#pragma unroll
        for (int ks = 0; ks < 8; ks++) {
            unsigned int v = gr[(size_t)ks * (NN * NN / 2) + t];
            union { unsigned int u; _Float16 h[2]; } cv; cv.u = v;
            g0 += (float)cv.h[0];
            g1 += (float)cv.h[1];
        }
    }

    float apv, anv; int api, ani;
    {
        // j0 = 2t processed first; tie-break "first index" => strict compares
        float dd0 = ni + nj2.x - 2.0f * g0;
        float dist0 = sqrtf(fmaxf(dd0, 1e-12f));
        bool pos0 = (tg2.x == tgt_i);
        apv = pos0 ? dist0 : -BIGF; api = 2 * t;
        anv = pos0 ? BIGF : dist0;  ani = 2 * t;
        float dd1 = ni + nj2.y - 2.0f * g1;
        float dist1 = sqrtf(fmaxf(dd1, 1e-12f));
        bool pos1 = (tg2.y == tgt_i);
        float a1 = pos1 ? dist1 : -BIGF;
        if (a1 > apv) { apv = a1; api = 2 * t + 1; }
        float b1 = pos1 ? BIGF : dist1;
        if (b1 < anv) { anv = b1; ani = 2 * t + 1; }
    }
    // wave reduction with first-index tie-break (matches jnp.argmax/argmin)
    for (int off = 32; off > 0; off >>= 1) {
        float av = __shfl_down(apv, off); int ai = __shfl_down(api, off);
        if (av > apv || (av == apv && ai < api)) { apv = av; api = ai; }
        float nv = __shfl_down(anv, off); int nid = __shfl_down(ani, off);
        if (nv < anv || (nv == anv && nid < ani)) { anv = nv; ani = nid; }
    }
    if (lane == 0) { sm.m.apv[w] = apv; sm.m.api[w] = api;
                     sm.m.anv[w] = anv; sm.m.ani[w] = ani; }
    __syncthreads();
    if (t == 0) {
        for (int wv = 1; wv < 4; wv++) {
            float av = sm.m.apv[wv]; int ai = sm.m.api[wv];
            if (av > apv || (av == apv && ai < api)) { apv = av; api = ai; }
            float nv = sm.m.anv[wv]; int nid = sm.m.ani[wv];
            if (nv < anv || (nv == anv && nid < ani)) { anv = nv; ani = nid; }
        }
        sm.m.pn[0] = api;
        sm.m.pn[1] = ani;
        atomicAdd(gsum, fmaxf(0.0f, MARGIN + apv - anv));
    }
    // stage A2 (prefetched at kernel start) while t0 finishes the reduce
    ((float4*)sm.m.A2)[t] = a2v;
    __syncthreads();

    // phase B2: local DTW. wave 0 = positive pair, wave 1 = negative pair.
    if (w < 2) {
        int ind = sm.m.pn[w];
        const float4* B4 = (const float4*)(LF + (size_t)ind * LDIM * PARTS);
        float4* Bw = (float4*)sm.m.B2[w];
        Bw[lane]       = B4[lane];
        Bw[lane + 64]  = B4[lane + 64];
        Bw[lane + 128] = B4[lane + 128];
        Bw[lane + 192] = B4[lane + 192];
    }
    __syncthreads();

    if (w < 2) {
        int p = lane >> 3, q = lane & 7;
        float acc = 0.0f;
        const float* Bw = sm.m.B2[w];
        for (int d = 0; d < LDIM; d++) {
            float diff = sm.m.A2[d * PARTS + p] - Bw[d * PARTS + q];
            acc = fmaf(diff, diff, acc);
        }
        float dist = sqrtf(fmaxf(acc, 1e-12f));
        sm.m.dtm[w][p * 8 + q] = tanhf(0.5f * dist);
    }
    __syncthreads();

    if ((t == 0) || (t == 64)) {
        const float* dm = sm.m.dtm[w];
        float dp[8];
        dp[0] = dm[0];
        for (int j = 1; j < 8; j++) dp[j] = dp[j - 1] + dm[j];
        for (int rr2 = 1; rr2 < 8; rr2++) {
            dp[0] += dm[rr2 * 8];
            for (int j = 1; j < 8; j++)
                dp[j] = dm[rr2 * 8 + j] + fminf(dp[j], dp[j - 1]);
        }
        sm.m.res[w] = dp[7];
    }
    __syncthreads();

    if (t == 0) {
        float l = fmaxf(0.0f, MARGIN + sm.m.res[0] - sm.m.res[1]);
        atomicAdd(lsum, l);
        __threadfence();
        unsigned old = atomicAdd(fin, 1u);
        if (old == (NN - 1)) {
            __threadfence();
            float ls = atomicAdd(lsum, 0.0f);
            float gs = atomicAdd(gsum, 0.0f);
            out[0] = gs * (1.0f / NN);
            out[1] = ls * (1.0f / NN);
        }
    }
}

// ---------------------------------------------------------------------------
extern "C" void kernel_launch(void* const* d_in, const int* in_sizes, int n_in,
                              void* d_out, int out_size, void* d_ws, size_t ws_size,
                              hipStream_t stream)
{
    const float* X  = (const float*)d_in[0];   // [512, 2048] fp32
    const int*   tg = (const int*)d_in[1];     // [512] int
    const float* LF = (const float*)d_in[2];   // [512, 128, 8] fp32
    float* out = (float*)d_out;                // 2 fp32 scalars

    char* ws = (char*)d_ws;
    _Float16* Gp   = (_Float16*)ws;            // 8 x 512 KB fp16 partials
    char* ctrl     = ws + (4u << 20);
    float* nsum    = (float*)ctrl;             // 512 fp32 summed norms
    float* gsum    = (float*)(ctrl + 2048);
    float* lsum    = (float*)(ctrl + 2052);
    unsigned* done = (unsigned*)(ctrl + 2056);
    unsigned* fin  = (unsigned*)(ctrl + 2060);

    hipMemsetAsync(ctrl, 0, 2064, stream);     // zero nsum + control block
    k_fused<<<NN, 256, 0, stream>>>(X, tg, LF, Gp, nsum, gsum, lsum, done, fin, out);
}

// Round 2
// 93.734 us; speedup vs baseline: 2.3988x; 2.3988x over previous
//
#include <hip/hip_runtime.h>
#include <math.h>

#define MARGIN 0.3f
#define BIGF 1e9f
#define NN 512
#define DD 2048
#define LDIM 128
#define PARTS 8

typedef __attribute__((ext_vector_type(8))) __bf16 bf16x8;
typedef __attribute__((ext_vector_type(4))) float f32x4;

// ---------------------------------------------------------------------------
// K1: G = X X^T via single-bf16 MFMA. 64x64 tiles, split-K=8, grid 512 =
//     2 blocks/CU. Double-buffered LDS. Partials stored as fp16 (err ~1e-3
//     on dist; threshold 7.25e-2). Norms harvested fp32 off the diagonal.
//     (verbatim from the verified 94.25 us version)
// ---------------------------------------------------------------------------
__global__ __launch_bounds__(256, 2) void k_gram(
    const float* __restrict__ X, _Float16* __restrict__ Gp,
    float* __restrict__ ndiag, float* gsum, float* lsum, unsigned* counter)
{
    __shared__ __bf16 A[2][4096], B[2][4096];   // 32 KB

    int bid = blockIdx.x;
    int tj = bid & 7, ti = (bid >> 3) & 7, ks = bid >> 6;
    int t = threadIdx.x;
    int w = t >> 6, lane = t & 63;
    int wr = w >> 1, wc = w & 1;

    if (bid == 0 && t == 0) { *gsum = 0.0f; *lsum = 0.0f; *counter = 0u; }

    int m = t >> 7;
    int r = (t >> 1) & 63;
    int kst = t & 1;
    int grow = (m ? tj : ti) * 64 + r;
    const float4* gp4 = (const float4*)(X + (size_t)grow * DD + ks * 256 + kst * 32);
    int ebase = kst * 2048 + (r >> 4) * 512 + (r & 15) * 8;

    float4 cur[8];
#pragma unroll
    for (int q = 0; q < 8; q++) cur[q] = gp4[q];

    f32x4 acc00 = {0.f, 0.f, 0.f, 0.f};
    f32x4 acc01 = {0.f, 0.f, 0.f, 0.f};
    f32x4 acc10 = {0.f, 0.f, 0.f, 0.f};
    f32x4 acc11 = {0.f, 0.f, 0.f, 0.f};

    {
        __bf16* hb = (m ? B[0] : A[0]) + ebase;
#pragma unroll
        for (int jg = 0; jg < 4; jg++) {
            float fe[8] = {cur[2 * jg].x, cur[2 * jg].y, cur[2 * jg].z, cur[2 * jg].w,
                           cur[2 * jg + 1].x, cur[2 * jg + 1].y, cur[2 * jg + 1].z, cur[2 * jg + 1].w};
            bf16x8 h;
#pragma unroll
            for (int e = 0; e < 8; e++) h[e] = (__bf16)fe[e];
            *(bf16x8*)(hb + jg * 128) = h;
        }
    }

#pragma unroll
    for (int it = 0; it < 4; ++it) {
        __syncthreads();                       // buf[it&1] staged & prior reads done
        if (it < 3) {
            const float4* np = gp4 + (it + 1) * 16;
#pragma unroll
            for (int q = 0; q < 8; q++) cur[q] = np[q];
        }
        int buf = it & 1;
#pragma unroll
        for (int kstep = 0; kstep < 2; kstep++) {
            const bf16x8* fA = (const bf16x8*)&A[buf][kstep * 2048 + wr * 1024];
            const bf16x8* fB = (const bf16x8*)&B[buf][kstep * 2048 + wc * 1024];
            bf16x8 ah0 = fA[lane], ah1 = fA[lane + 64];
            bf16x8 bh0 = fB[lane], bh1 = fB[lane + 64];
            acc00 = __builtin_amdgcn_mfma_f32_16x16x32_bf16(ah0, bh0, acc00, 0, 0, 0);
            acc01 = __builtin_amdgcn_mfma_f32_16x16x32_bf16(ah0, bh1, acc01, 0, 0, 0);
            acc10 = __builtin_amdgcn_mfma_f32_16x16x32_bf16(ah1, bh0, acc10, 0, 0, 0);
            acc11 = __builtin_amdgcn_mfma_f32_16x16x32_bf16(ah1, bh1, acc11, 0, 0, 0);
        }
        if (it < 3) {
            int nb = (it + 1) & 1;
            __bf16* hb = (m ? B[nb] : A[nb]) + ebase;
#pragma unroll
            for (int jg = 0; jg < 4; jg++) {
                float fe[8] = {cur[2 * jg].x, cur[2 * jg].y, cur[2 * jg].z, cur[2 * jg].w,
                               cur[2 * jg + 1].x, cur[2 * jg + 1].y, cur[2 * jg + 1].z, cur[2 * jg + 1].w};
                bf16x8 h;
#pragma unroll
                for (int e = 0; e < 8; e++) h[e] = (__bf16)fe[e];
                *(bf16x8*)(hb + jg * 128) = h;
            }
        }
    }

    // epilogue: C/D layout col = lane&15, row = (lane>>4)*4 + reg
    int rbase = ti * 64 + wr * 32 + ((lane >> 4) << 2);
    int cbase = tj * 64 + wc * 32 + (lane & 15);
    _Float16* gb = Gp + (size_t)ks * NN * NN;
    f32x4 accs[2][2] = {{acc00, acc01}, {acc10, acc11}};
#pragma unroll
    for (int g = 0; g < 2; g++)
#pragma unroll
        for (int h = 0; h < 2; h++)
#pragma unroll
            for (int rr = 0; rr < 4; rr++)
                gb[(size_t)(rbase + g * 16 + rr) * NN + cbase + h * 16] =
                    (_Float16)accs[g][h][rr];

    // diagonal harvest (fp32): lanes holding row==col in diagonal tiles
    if (ti == tj && wr == wc && ((lane >> 4) == ((lane & 15) >> 2))) {
        int rr = lane & 3;
        int row0 = rbase + rr;
        ndiag[ks * NN + row0]      = acc00[rr];
        ndiag[ks * NN + row0 + 16] = acc11[rr];
    }
}

// ---------------------------------------------------------------------------
// K2: fused hard mining + local DTW loss + finalize.
//     Front-end vectorized vs round 0: Gp partials as uint (2xfp16/load,
//     8 loads instead of 16 scalars), ndiag as float2, tg as int2.
//     j-mapping per thread: (2t, 2t+1); in-thread order preserves the
//     first-index tie-break, cross-lane reduce keeps explicit index compare.
// ---------------------------------------------------------------------------
__global__ __launch_bounds__(256) void k_mine_local(
    const _Float16* __restrict__ Gp, const float* __restrict__ ndiag,
    const int* __restrict__ tg, const float* __restrict__ LF,
    float* gsum, float* lsum, unsigned* counter, float* __restrict__ out)
{
    __shared__ float s_apv[4]; __shared__ int s_api[4];
    __shared__ float s_anv[4]; __shared__ int s_ani[4];
    __shared__ int sh_pn[2];
    __shared__ float A2[LDIM * PARTS];
    __shared__ float B2[2][LDIM * PARTS];
    __shared__ float dtm[2][64];
    __shared__ float res[2];

    int i = blockIdx.x;
    int t = threadIdx.x;
    int lane = t & 63, w = t >> 6;

    // prefetch lf[i] (independent of mining)
    float4 a2v = ((const float4*)(LF + (size_t)i * LDIM * PARTS))[t];

    float ni = 0.f, nj0 = 0.f, nj1 = 0.f;
    float g0 = 0.f, g1 = 0.f;
    const unsigned* gr = (const unsigned*)Gp + (size_t)i * (NN / 2);
#pragma unroll
    for (int ks = 0; ks < 8; ks++) {
        ni += ndiag[ks * NN + i];               // uniform -> scalar broadcast
        float2 nd = ((const float2*)(ndiag + ks * NN))[t];
        nj0 += nd.x; nj1 += nd.y;
        unsigned v = gr[(size_t)ks * (NN * NN / 2) + t];
        union { unsigned u; _Float16 h[2]; } cv; cv.u = v;
        g0 += (float)cv.h[0];
        g1 += (float)cv.h[1];
    }
    int2 tg2 = ((const int2*)tg)[t];
    int tgt_i = tg[i];

    float apv, anv; int api, ani;
    {
        // j0 = 2t processed first; "first index" tie-break => strict compares
        float dd0 = ni + nj0 - 2.0f * g0;
        float dist0 = sqrtf(fmaxf(dd0, 1e-12f));
        bool pos0 = (tg2.x == tgt_i);
        apv = pos0 ? dist0 : -BIGF; api = 2 * t;
        anv = pos0 ? BIGF : dist0;  ani = 2 * t;
        float dd1 = ni + nj1 - 2.0f * g1;
        float dist1 = sqrtf(fmaxf(dd1, 1e-12f));
        bool pos1 = (tg2.y == tgt_i);
        float a1 = pos1 ? dist1 : -BIGF;
        if (a1 > apv) { apv = a1; api = 2 * t + 1; }
        float b1 = pos1 ? BIGF : dist1;
        if (b1 < anv) { anv = b1; ani = 2 * t + 1; }
    }
    // wave reduction with first-index tie-break (matches jnp.argmax/argmin)
    for (int off = 32; off > 0; off >>= 1) {
        float av = __shfl_down(apv, off); int ai = __shfl_down(api, off);
        if (av > apv || (av == apv && ai < api)) { apv = av; api = ai; }
        float nv = __shfl_down(anv, off); int nid = __shfl_down(ani, off);
        if (nv < anv || (nv == anv && nid < ani)) { anv = nv; ani = nid; }
    }
    if (lane == 0) { s_apv[w] = apv; s_api[w] = api;
                     s_anv[w] = anv; s_ani[w] = ani; }
    __syncthreads();
    if (t == 0) {
        for (int wv = 1; wv < 4; wv++) {
            float av = s_apv[wv]; int ai = s_api[wv];
            if (av > apv || (av == apv && ai < api)) { apv = av; api = ai; }
            float nv = s_anv[wv]; int nid = s_ani[wv];
            if (nv < anv || (nv == anv && nid < ani)) { anv = nv; ani = nid; }
        }
        sh_pn[0] = api;
        sh_pn[1] = ani;
        atomicAdd(gsum, fmaxf(0.0f, MARGIN + apv - anv));
    }
    // stage A2 (prefetched at kernel start) while t0 finishes the reduce
    ((float4*)A2)[t] = a2v;
    __syncthreads();

    // phase 2: local DTW loss. wave 0 = positive pair, wave 1 = negative pair.
    if (w < 2) {
        int ind = sh_pn[w];
        const float4* B4 = (const float4*)(LF + (size_t)ind * LDIM * PARTS);
        float4* Bw = (float4*)B2[w];
        Bw[lane]       = B4[lane];
        Bw[lane + 64]  = B4[lane + 64];
        Bw[lane + 128] = B4[lane + 128];
        Bw[lane + 192] = B4[lane + 192];
    }
    __syncthreads();

    if (w < 2) {
        int p = lane >> 3, q = lane & 7;
        float acc = 0.0f;
        const float* Bw = B2[w];
        for (int d = 0; d < LDIM; d++) {
            float diff = A2[d * PARTS + p] - Bw[d * PARTS + q];
            acc = fmaf(diff, diff, acc);
        }
        float dist = sqrtf(fmaxf(acc, 1e-12f));
        dtm[w][p * 8 + q] = tanhf(0.5f * dist);
    }
    __syncthreads();

    if ((t == 0) || (t == 64)) {
        const float* dm = dtm[w];
        float dp[8];
        dp[0] = dm[0];
        for (int j = 1; j < 8; j++) dp[j] = dp[j - 1] + dm[j];
        for (int rr = 1; rr < 8; rr++) {
            dp[0] += dm[rr * 8];
            for (int j = 1; j < 8; j++)
                dp[j] = dm[rr * 8 + j] + fminf(dp[j], dp[j - 1]);
        }
        res[w] = dp[7];
    }
    __syncthreads();

    if (t == 0) {
        float l = fmaxf(0.0f, MARGIN + res[0] - res[1]);
        atomicAdd(lsum, l);
        __threadfence();
        unsigned old = atomicAdd(counter, 1u);
        if (old == (NN - 1)) {
            __threadfence();
            float ls = atomicAdd(lsum, 0.0f);
            float gs = atomicAdd(gsum, 0.0f);
            out[0] = gs * (1.0f / NN);
            out[1] = ls * (1.0f / NN);
        }
    }
}

// ---------------------------------------------------------------------------
extern "C" void kernel_launch(void* const* d_in, const int* in_sizes, int n_in,
                              void* d_out, int out_size, void* d_ws, size_t ws_size,
                              hipStream_t stream)
{
    const float* X  = (const float*)d_in[0];   // [512, 2048] fp32
    const int*   tg = (const int*)d_in[1];     // [512] int
    const float* LF = (const float*)d_in[2];   // [512, 128, 8] fp32
    float* out = (float*)d_out;                // 2 fp32 scalars

    char* ws = (char*)d_ws;
    _Float16* Gp      = (_Float16*)ws;                       // 8 x 512 KB fp16 partials
    float*    ndiag   = (float*)(ws + (4u << 20));           // 16 KB
    float*    gsum    = (float*)(ws + (4u << 20) + 16384);
    float*    lsum    = (float*)(ws + (4u << 20) + 16388);
    unsigned* counter = (unsigned*)(ws + (4u << 20) + 16392);

    k_gram<<<512, 256, 0, stream>>>(X, Gp, ndiag, gsum, lsum, counter);
    k_mine_local<<<512, 256, 0, stream>>>(Gp, ndiag, tg, LF, gsum, lsum, counter, out);
}